// Round 5
// baseline (1019.487 us; speedup 1.0000x reference)
//
#include <hip/hip_runtime.h>
#include <math.h>

// B=32, C=12, H=64, W=64, hidden=128, cond_c=4, out_spline=276 (pad->288=12*24)
// NUM_BINS=8, TAIL=3.0, MBW=MBH=MD=0.001

#define NPIX 4096
#define NY   1572864

typedef _Float16 half8 __attribute__((ext_vector_type(8)));
typedef _Float16 half4 __attribute__((ext_vector_type(4)));
typedef float f32x4 __attribute__((ext_vector_type(4)));

// async global->LDS, 16B per lane: HW writes LDS base + lane*16; ldst must be wave-uniform
#define ASYNC16(gsrc, ldst) \
  __builtin_amdgcn_global_load_lds((const __attribute__((address_space(1))) unsigned int*)(gsrc), \
                                   (__attribute__((address_space(3))) unsigned int*)(ldst), 16, 0, 0)

// h2p layout: [b][cc=ci/32][pp=66*66][ci%32] fp16, halo ring of zeros
#define H2P_PLANE 4356            // 66*66
#define H2P_IDX(b, cc, pp) ((((size_t)(b) * 4 + (cc)) * H2P_PLANE + (pp)) << 5)

// ---------------------------------------------------------------------------
// prep: weight packs + logdet init
//   w1 (128,16,3,3)  -> w1t[(ci*9+tap)*128 + oc]                 fp32
//   w2 (128,128,1,1) -> w2h[(ks*128+oc)*32 + km]  (ci=ks*32+km)  fp16
//   w3 (276,128,3,3) -> w3h[((t*4+cc)*288 + oc')*32 + cim]       fp16
//                       oc' = c*24 + j (j<23 real, j=23 zero pad)
// ---------------------------------------------------------------------------
__global__ __launch_bounds__(256) void prep_k(
    const float* __restrict__ w1, const float* __restrict__ w2,
    const float* __restrict__ w3, float* __restrict__ w1t,
    _Float16* __restrict__ w2h, _Float16* __restrict__ w3h,
    const float* __restrict__ logdet, float* __restrict__ ld_out)
{
    const int i = blockIdx.x * 256 + threadIdx.x;   // < 331776
    if (i < 18432) {
        int oc = i / 144, r = i % 144;
        w1t[r * 128 + oc] = w1[i];
    }
    if (i < 16384) {                     // w2h
        int km = i & 31, oc = (i >> 5) & 127, ks = i >> 12;
        w2h[i] = (_Float16)w2[oc * 128 + ks * 32 + km];
    }
    {   // w3h: flat i = ((t*4+cc)*288 + oc)*32 + cim
        int cim = i & 31;
        int oc = (i >> 5) % 288;
        int tc = i / (288 * 32);        // 0..35
        int t = tc >> 2, cc = tc & 3;
        int c = oc / 24, j = oc % 24;
        int ci = cc * 32 + cim;
        float v = (j < 23) ? w3[((c * 23 + j) * 128 + ci) * 9 + t] : 0.f;
        w3h[i] = (_Float16)v;
    }
    if (i < 32) ld_out[i] = logdet[i];
}

// ---------------------------------------------------------------------------
// zero the halo ring of h2p (260 border pixels per (b,cc) plane)
// ---------------------------------------------------------------------------
__global__ __launch_bounds__(256) void zring_k(_Float16* __restrict__ h2p)
{
    const int i = blockIdx.x * 256 + threadIdx.x;
    if (i >= 133120) return;
    const int q = i & 3;
    const int rest = i >> 2;
    const int r = rest % 260;
    const int cc = (rest / 260) & 3;
    const int b = rest / 1040;
    int pp;
    if (r < 66)       pp = r;
    else if (r < 132) pp = 65 * 66 + (r - 66);
    else if (r < 196) pp = (r - 131) * 66;
    else              pp = (r - 195) * 66 + 65;
    f32x4 z = {0.f, 0.f, 0.f, 0.f};
    *(f32x4*)(h2p + H2P_IDX(b, cc, pp) + q * 8) = z;
}

// ---------------------------------------------------------------------------
// conv1: 3x3 SAME, 16->128, +bias+relu -> h1p fp16, layout [b][pix][128 oc]
// ---------------------------------------------------------------------------
__global__ __launch_bounds__(64) void conv1_k(
    const float* __restrict__ x, const float* __restrict__ cond,
    const float* __restrict__ w1t, const float* __restrict__ b1,
    _Float16* __restrict__ h1p)
{
    const int w = threadIdx.x;
    const int ocb = blockIdx.x * 16;
    const int h = blockIdx.y;
    const int b = blockIdx.z;

    float acc[16];
#pragma unroll
    for (int j = 0; j < 16; ++j) acc[j] = b1[ocb + j];

    for (int ci = 0; ci < 16; ++ci) {
        const float* src = (ci < 12) ? (x + ((size_t)(b * 12 + ci)) * NPIX)
                                     : (cond + ((size_t)(b * 4 + (ci - 12))) * NPIX);
#pragma unroll
        for (int dy = -1; dy <= 1; ++dy) {
            const int hh = h + dy;
            const bool hv = (hh >= 0) && (hh < 64);
#pragma unroll
            for (int dx = -1; dx <= 1; ++dx) {
                const int ww = w + dx;
                const float v = (hv && ww >= 0 && ww < 64) ? src[hh * 64 + ww] : 0.f;
                const float* wp = w1t + (ci * 9 + (dy + 1) * 3 + (dx + 1)) * 128 + ocb;
#pragma unroll
                for (int j = 0; j < 16; ++j) acc[j] = fmaf(v, wp[j], acc[j]);
            }
        }
    }
    _Float16 tmp[16];
#pragma unroll
    for (int j = 0; j < 16; ++j) tmp[j] = (_Float16)fmaxf(acc[j], 0.f);
    _Float16* dst = h1p + ((size_t)((b << 12) + h * 64 + w) << 7) + ocb;
    *(half8*)dst       = *(half8*)tmp;
    *(half8*)(dst + 8) = *(half8*)(tmp + 8);
}

// ---------------------------------------------------------------------------
// conv2 as MFMA GEMM: M=pixels, N=128 oc, K=128. Whole w2 (32 KB fp16) staged
// in LDS once. Block = 256 thr (4 waves) x 256 pixels; wave = 64 pix x 128 oc
// (acc 4pt x 8ot = 128 regs). bias+relu epilogue, direct h2p stores.
// ---------------------------------------------------------------------------
__global__ __launch_bounds__(256, 2) void conv2_k(
    const _Float16* __restrict__ h1p, const _Float16* __restrict__ w2h,
    const float* __restrict__ b2, _Float16* __restrict__ h2p)
{
    __shared__ __align__(16) char smem[33280];   // w2l 32768 + b2l 512
    float* b2l = (float*)(smem + 32768);
    const int tid = threadIdx.x;
    const int wv = tid >> 6, lane = tid & 63;
    const int row16 = lane & 15, quad = lane >> 4;
    const int ptile = blockIdx.x;
    const int b = ptile >> 4;
    const int pim0 = (ptile & 15) << 8;

    if (tid < 128) b2l[tid] = b2[tid];
#pragma unroll
    for (int k = 0; k < 8; ++k) {
        const int c0 = k * 256 + wv * 64;
        ASYNC16(w2h + (size_t)(c0 + lane) * 8, smem + c0 * 16);
    }

    f32x4 acc[4][8];
#pragma unroll
    for (int pt = 0; pt < 4; ++pt)
#pragma unroll
        for (int ot = 0; ot < 8; ++ot) acc[pt][ot] = (f32x4){0.f, 0.f, 0.f, 0.f};

    const int pixbase = (b << 12) + pim0 + wv * 64;
    __syncthreads();

#pragma unroll
    for (int ks = 0; ks < 4; ++ks) {
        half8 bf[4], af[8];
#pragma unroll
        for (int pt = 0; pt < 4; ++pt)
            bf[pt] = *(const half8*)(h1p + ((size_t)(pixbase + pt * 16 + row16) << 7) + ks * 32 + quad * 8);
        const _Float16* wl = (const _Float16*)smem;
#pragma unroll
        for (int ot = 0; ot < 8; ++ot)
            af[ot] = *(const half8*)(wl + ((ks * 128 + ot * 16 + row16) << 5) + quad * 8);
#pragma unroll
        for (int ot = 0; ot < 8; ++ot)
#pragma unroll
            for (int pt = 0; pt < 4; ++pt)
                acc[pt][ot] = __builtin_amdgcn_mfma_f32_16x16x32_f16(af[ot], bf[pt], acc[pt][ot], 0, 0, 0);
    }

    // epilogue: C lane holds pixel=row16(-tile), oc=ot*16+quad*4+r
#pragma unroll
    for (int pt = 0; pt < 4; ++pt) {
        const int p = pim0 + wv * 64 + pt * 16 + row16;      // within-image pixel
        const int pp = ((p >> 6) + 1) * 66 + (p & 63) + 1;
#pragma unroll
        for (int ot = 0; ot < 8; ++ot) {
            const int oc0 = ot * 16 + quad * 4;
            half4 v;
#pragma unroll
            for (int r = 0; r < 4; ++r)
                v[r] = (_Float16)fmaxf(acc[pt][ot][r] + b2l[oc0 + r], 0.f);
            *(half4*)(h2p + H2P_IDX(b, oc0 >> 5, pp) + (oc0 & 31)) = v;
        }
    }
}

// ---------------------------------------------------------------------------
// RQS spline evaluation for one element, given its 23 params in prm[].
// ---------------------------------------------------------------------------
__device__ __forceinline__ void rqs_eval(const float* prm, float xv,
                                         float& yv_out, float& lad_out)
{
    const float xin = fminf(fmaxf(xv, -3.f), 3.f);

    float mw = prm[0], mh = prm[8];
#pragma unroll
    for (int j = 1; j < 8; ++j) { mw = fmaxf(mw, prm[j]); mh = fmaxf(mh, prm[8 + j]); }
    float ew[8], eh[8];
    float sw = 0.f, sh = 0.f;
#pragma unroll
    for (int j = 0; j < 8; ++j) {
        ew[j] = expf(prm[j] - mw);      sw += ew[j];
        eh[j] = expf(prm[8 + j] - mh);  sh += eh[j];
    }
    const float rw = 1.f / sw, rh = 1.f / sh;

    const float CONST_D = logf(expf(0.999f) - 1.f);

    float cumw = 0.f, cumh = 0.f;
    float cw_lo = -3.f, ch_lo = -3.f;
    float in_cw = 0.f, in_w = 1.f, in_ch = 0.f, in_h = 1.f, sd0 = 0.f, sd1 = 0.f;
#pragma unroll
    for (int i = 0; i < 8; ++i) {
        cumw += fmaf(0.992f, ew[i] * rw, 0.001f);
        cumh += fmaf(0.992f, eh[i] * rh, 0.001f);
        const float cw_hi = (i == 7) ? 3.f : fmaf(6.f, cumw, -3.f);
        const float ch_hi = (i == 7) ? 3.f : fmaf(6.f, cumh, -3.f);
        const bool sel = (xin >= cw_lo) && ((i == 7) || (xin < cw_hi));
        in_cw = sel ? cw_lo : in_cw;
        in_w  = sel ? (cw_hi - cw_lo) : in_w;
        in_ch = sel ? ch_lo : in_ch;
        in_h  = sel ? (ch_hi - ch_lo) : in_h;
        sd0   = sel ? ((i == 0) ? CONST_D : prm[16 + i - 1]) : sd0;
        sd1   = sel ? ((i == 7) ? CONST_D : prm[16 + i]) : sd1;
        cw_lo = cw_hi; ch_lo = ch_hi;
    }

    const float d0 = 0.001f + ((sd0 > 20.f) ? sd0 : log1pf(expf(sd0)));
    const float d1 = 0.001f + ((sd1 > 20.f) ? sd1 : log1pf(expf(sd1)));

    const float delta = in_h / in_w;
    const float theta = (xin - in_cw) / in_w;
    const float omt = 1.f - theta;
    const float tom = theta * omt;
    const float th2 = theta * theta;
    const float numer = in_h * (delta * th2 + d0 * tom);
    const float denom = delta + (d0 + d1 - 2.f * delta) * tom;
    float yv = in_ch + numer / denom;
    const float dnum = delta * delta * (d1 * th2 + 2.f * delta * tom + d0 * omt * omt);
    float lad = logf(dnum) - 2.f * logf(denom);

    const bool inside = (xv >= -3.f) && (xv <= 3.f);
    yv_out = inside ? yv : xv;
    lad_out = inside ? lad : 0.f;
}

// ---------------------------------------------------------------------------
// conv3 v3: implicit-GEMM MFMA with LDS staging (m97 structure).
// Block = 256 thr (4 waves), 256 pixels (4 rows) x 144 oc' (col half).
// LDS: act single buffer (6 padded rows x 66 x 32ci = 25344 B, restaged per cc,
//      contiguous memcpy from h2p), wt double-buffered 2 x 9216 B, b3l 576 B.
// K-loop: 36 steps (cc outer, t inner): barrier; issue next-wt stage; 13
// ds_read_b128 frags; 36 MFMAs. acc 144 + frags 52 + temps < 256 => no spill.
// Epilogue: LDS round-trip (overlays staging bufs) + RQS + logdet atomics.
// ---------------------------------------------------------------------------
__global__ __launch_bounds__(256, 2) void conv3_rqs_k(
    const _Float16* __restrict__ h2p, const _Float16* __restrict__ w3h,
    const float* __restrict__ b3, const float* __restrict__ x,
    float* __restrict__ y, float* __restrict__ ld_out)
{
    __shared__ __align__(16) char smem[44352];
    // act [0,25344)  wt0 [25344,34560)  wt1 [34560,43776)  b3l [43776,44352)
    // epilogue overlay: epi 4x9216 = [0,36864)  (b3l untouched)
    float* b3l = (float*)(smem + 43776);

    const int tid = threadIdx.x;
    const int wv = tid >> 6, lane = tid & 63;
    const int row16 = lane & 15, quad = lane >> 4;
    const int col = blockIdx.x;            // 0..1 -> oc' base col*144
    const int ptile = blockIdx.y;          // 0..511
    const int b = ptile >> 4;
    const int pim0 = (ptile & 15) << 8;
    const int h0 = pim0 >> 6;              // base row, multiple of 4

    if (tid < 144) {
        const int c = tid / 24, j = tid % 24;
        b3l[tid] = (j < 23) ? b3[(col * 6 + c) * 23 + j] : 0.f;
    }

    f32x4 acc[4][9];
#pragma unroll
    for (int pt = 0; pt < 4; ++pt)
#pragma unroll
        for (int ot = 0; ot < 9; ++ot) acc[pt][ot] = (f32x4){0.f, 0.f, 0.f, 0.f};

    // --- staging helpers (contiguous global->LDS memcpy via global_load_lds) ---
    auto stage_wt = [&](int t, int cc, int buf) {
        const _Float16* gw = w3h + ((size_t)((t * 4 + cc) * 288 + col * 144) << 5);
        char* wb = smem + 25344 + buf * 9216;         // 9216 B = 576 chunks
        const int c0 = wv * 64;
        ASYNC16(gw + (size_t)(c0 + lane) * 8, wb + c0 * 16);
        const int c1 = 256 + wv * 64;
        ASYNC16(gw + (size_t)(c1 + lane) * 8, wb + c1 * 16);
        if (wv == 0) ASYNC16(gw + (size_t)(512 + lane) * 8, wb + 512 * 16);
    };
    auto stage_act = [&](int cc) {
        const _Float16* ga = h2p + H2P_IDX(b, cc, h0 * 66);   // 25344 B contiguous
#pragma unroll
        for (int k = 0; k < 6; ++k) {
            const int c0 = k * 256 + wv * 64;
            ASYNC16(ga + (size_t)(c0 + lane) * 8, smem + c0 * 16);
        }
        if (wv == 0 && lane < 48)
            ASYNC16(ga + (size_t)(1536 + lane) * 8, smem + 1536 * 16);
    };

    stage_act(0);
    stage_wt(0, 0, 0);

    for (int cc = 0; cc < 4; ++cc) {
        for (int t = 0; t < 9; ++t) {
            const int step = cc * 9 + t;
            __syncthreads();               // staged data ready; prev buffers free
            if (step + 1 < 36) {
                const int t1 = (t == 8) ? 0 : t + 1;
                const int cc1 = (t == 8) ? cc + 1 : cc;
                stage_wt(t1, cc1, (step + 1) & 1);
            }
            const _Float16* act = (const _Float16*)smem;
            const _Float16* wt = (const _Float16*)(smem + 25344 + (step & 1) * 9216);
            const int dy = t / 3, dx = t % 3;
            half8 bf[4], af[9];
#pragma unroll
            for (int pt = 0; pt < 4; ++pt)
                bf[pt] = *(const half8*)(act + (((wv + dy) * 66 + dx + pt * 16 + row16) << 5) + quad * 8);
#pragma unroll
            for (int ot = 0; ot < 9; ++ot)
                af[ot] = *(const half8*)(wt + ((ot * 16 + row16) << 5) + quad * 8);
#pragma unroll
            for (int ot = 0; ot < 9; ++ot)
#pragma unroll
                for (int pt = 0; pt < 4; ++pt)
                    acc[pt][ot] = __builtin_amdgcn_mfma_f32_16x16x32_f16(af[ot], bf[pt], acc[pt][ot], 0, 0, 0);
            if (t == 8 && cc < 3) {
                __syncthreads();           // act buffer dead for all waves
                stage_act(cc + 1);
            }
        }
    }
    __syncthreads();

    // ---- epilogue: wave-private LDS region, 16 pix x 144 oc' fp32 per pass ----
    float* epi = (float*)smem + wv * 2304;
    float lad_acc = 0.f;
#pragma unroll 1
    for (int pt = 0; pt < 4; ++pt) {
#pragma unroll
        for (int ot = 0; ot < 9; ++ot)
            *(f32x4*)(epi + row16 * 144 + ot * 16 + quad * 4) = acc[pt][ot];
#pragma unroll 1
        for (int pass = 0; pass < 2; ++pass) {
            const int idx = pass * 64 + lane;
            if (idx < 96) {
                const int p16 = idx & 15, c = idx >> 4;       // c 0..5
                float prm[23];
#pragma unroll
                for (int j = 0; j < 23; ++j)
                    prm[j] = epi[p16 * 144 + c * 24 + j] + b3l[c * 24 + j];
                const int tpix = wv * 64 + pt * 16 + p16;
                const size_t xi = (((size_t)(b * 12 + col * 6 + c)) << 12) + (pim0 + tpix);
                const float xv = x[xi];
                float yv, lad;
                rqs_eval(prm, xv, yv, lad);
                y[xi] = yv;
                lad_acc += lad;
            }
        }
        __syncthreads();   // epi region reuse across pt
    }

#pragma unroll
    for (int off = 32; off > 0; off >>= 1) lad_acc += __shfl_down(lad_acc, off);
    if (lane == 0) atomicAdd(&ld_out[b], lad_acc);
}

// ---------------------------------------------------------------------------
extern "C" void kernel_launch(void* const* d_in, const int* in_sizes, int n_in,
                              void* d_out, int out_size, void* d_ws, size_t ws_size,
                              hipStream_t stream)
{
    const float* x      = (const float*)d_in[0];
    const float* logdet = (const float*)d_in[1];
    const float* cond   = (const float*)d_in[2];
    const float* w1     = (const float*)d_in[3];
    const float* b1     = (const float*)d_in[4];
    const float* w2     = (const float*)d_in[5];
    const float* b2     = (const float*)d_in[6];
    const float* w3     = (const float*)d_in[7];
    const float* b3     = (const float*)d_in[8];

    char* ws = (char*)d_ws;
    _Float16* h1p = (_Float16*)ws;                       // 33,554,432 B  [b][pix][128oc]
    _Float16* h2p = (_Float16*)(ws + 33554432);          // 35,684,352 B
    float*    w1t = (float*)(ws + 69238784);             // 73,728 B
    _Float16* w2h = (_Float16*)(ws + 69312512);          // 32,768 B
    _Float16* w3h = (_Float16*)(ws + 69345280);          // 663,552 B (end ~70 MB)

    float* y      = (float*)d_out;                       // NY floats
    float* ld_out = y + NY;                              // 32 floats

    prep_k<<<1296, 256, 0, stream>>>(w1, w2, w3, w1t, w2h, w3h, logdet, ld_out);
    zring_k<<<520, 256, 0, stream>>>(h2p);
    conv1_k<<<dim3(8, 64, 32), 64, 0, stream>>>(x, cond, w1t, b1, h1p);
    conv2_k<<<512, 256, 0, stream>>>(h1p, w2h, b2, h2p);
    conv3_rqs_k<<<dim3(2, 512), 256, 0, stream>>>(h2p, w3h, b3, x, y, ld_out);
}

// Round 6
// 399.822 us; speedup vs baseline: 2.5499x; 2.5499x over previous
//
#include <hip/hip_runtime.h>
#include <math.h>

// B=32, C=12, H=64, W=64, hidden=128, cond_c=4, out_spline=276 (pad->288=12*24)
// NUM_BINS=8, TAIL=3.0, MBW=MBH=MD=0.001

#define NPIX 4096
#define NY   1572864

typedef _Float16 half8 __attribute__((ext_vector_type(8)));
typedef _Float16 half4 __attribute__((ext_vector_type(4)));
typedef float f32x4 __attribute__((ext_vector_type(4)));

// async global->LDS, 16B per lane: HW writes LDS base + lane*16; ldst wave-uniform
#define ASYNC16(gsrc, ldst) \
  __builtin_amdgcn_global_load_lds((const __attribute__((address_space(1))) unsigned int*)(gsrc), \
                                   (__attribute__((address_space(3))) unsigned int*)(ldst), 16, 0, 0)

// h2p layout: [b][cc=ci/32][pp=66*66][ci%32] fp16, halo ring of zeros
#define H2P_PLANE 4356            // 66*66
#define H2P_IDX(b, cc, pp) ((((size_t)(b) * 4 + (cc)) * H2P_PLANE + (pp)) << 5)

// ---------------------------------------------------------------------------
// prep: weight packs + logdet init
//   w1 (128,16,3,3)  -> w1t[(ci*9+tap)*128 + oc]                 fp32
//   w2 (128,128,1,1) -> w2h[(ks*128+oc)*32 + km]  (ci=ks*32+km)  fp16
//   w3 (276,128,3,3) -> w3h[((t*4+cc)*288 + oc')*32 + cim]       fp16
//                       oc' = c*24 + j (j<23 real, j=23 zero pad)
// ---------------------------------------------------------------------------
__global__ __launch_bounds__(256) void prep_k(
    const float* __restrict__ w1, const float* __restrict__ w2,
    const float* __restrict__ w3, float* __restrict__ w1t,
    _Float16* __restrict__ w2h, _Float16* __restrict__ w3h,
    const float* __restrict__ logdet, float* __restrict__ ld_out)
{
    const int i = blockIdx.x * 256 + threadIdx.x;   // < 331776
    if (i < 18432) {
        int oc = i / 144, r = i % 144;
        w1t[r * 128 + oc] = w1[i];
    }
    if (i < 16384) {                     // w2h
        int km = i & 31, oc = (i >> 5) & 127, ks = i >> 12;
        w2h[i] = (_Float16)w2[oc * 128 + ks * 32 + km];
    }
    {   // w3h: flat i = ((t*4+cc)*288 + oc)*32 + cim
        int cim = i & 31;
        int oc = (i >> 5) % 288;
        int tc = i / (288 * 32);        // 0..35
        int t = tc >> 2, cc = tc & 3;
        int c = oc / 24, j = oc % 24;
        int ci = cc * 32 + cim;
        float v = (j < 23) ? w3[((c * 23 + j) * 128 + ci) * 9 + t] : 0.f;
        w3h[i] = (_Float16)v;
    }
    if (i < 32) ld_out[i] = logdet[i];
}

// ---------------------------------------------------------------------------
// zero the halo ring of h2p (260 border pixels per (b,cc) plane)
// ---------------------------------------------------------------------------
__global__ __launch_bounds__(256) void zring_k(_Float16* __restrict__ h2p)
{
    const int i = blockIdx.x * 256 + threadIdx.x;
    if (i >= 133120) return;
    const int q = i & 3;
    const int rest = i >> 2;
    const int r = rest % 260;
    const int cc = (rest / 260) & 3;
    const int b = rest / 1040;
    int pp;
    if (r < 66)       pp = r;
    else if (r < 132) pp = 65 * 66 + (r - 66);
    else if (r < 196) pp = (r - 131) * 66;
    else              pp = (r - 195) * 66 + 65;
    f32x4 z = {0.f, 0.f, 0.f, 0.f};
    *(f32x4*)(h2p + H2P_IDX(b, cc, pp) + q * 8) = z;
}

// ---------------------------------------------------------------------------
// conv1: 3x3 SAME, 16->128, +bias+relu -> h1p fp16, layout [b][pix][128 oc]
// 32 oc per thread (halves address overhead and x re-reads vs 16).
// ---------------------------------------------------------------------------
__global__ __launch_bounds__(64) void conv1_k(
    const float* __restrict__ x, const float* __restrict__ cond,
    const float* __restrict__ w1t, const float* __restrict__ b1,
    _Float16* __restrict__ h1p)
{
    const int w = threadIdx.x;
    const int ocb = blockIdx.x * 32;
    const int h = blockIdx.y;
    const int b = blockIdx.z;

    float acc[32];
#pragma unroll
    for (int j = 0; j < 32; ++j) acc[j] = b1[ocb + j];

    for (int ci = 0; ci < 16; ++ci) {
        const float* src = (ci < 12) ? (x + ((size_t)(b * 12 + ci)) * NPIX)
                                     : (cond + ((size_t)(b * 4 + (ci - 12))) * NPIX);
#pragma unroll
        for (int dy = -1; dy <= 1; ++dy) {
            const int hh = h + dy;
            const bool hv = (hh >= 0) && (hh < 64);
#pragma unroll
            for (int dx = -1; dx <= 1; ++dx) {
                const int ww = w + dx;
                const float v = (hv && ww >= 0 && ww < 64) ? src[hh * 64 + ww] : 0.f;
                const float* wp = w1t + (ci * 9 + (dy + 1) * 3 + (dx + 1)) * 128 + ocb;
#pragma unroll
                for (int j = 0; j < 32; ++j) acc[j] = fmaf(v, wp[j], acc[j]);
            }
        }
    }
    _Float16 tmp[32];
#pragma unroll
    for (int j = 0; j < 32; ++j) tmp[j] = (_Float16)fmaxf(acc[j], 0.f);
    _Float16* dst = h1p + ((size_t)((b << 12) + h * 64 + w) << 7) + ocb;
#pragma unroll
    for (int q = 0; q < 4; ++q) *(half8*)(dst + q * 8) = *(half8*)(tmp + q * 8);
}

// ---------------------------------------------------------------------------
// conv2 as MFMA GEMM: M=pixels, N=128 oc, K=128. Whole w2 (32 KB fp16) staged
// in LDS once. Block = 256 thr (4 waves) x 256 pixels; wave = 64 pix x 128 oc
// (acc 4pt x 8ot = 128 regs). bias+relu epilogue, direct h2p stores.
// ---------------------------------------------------------------------------
__global__ __launch_bounds__(256, 2) void conv2_k(
    const _Float16* __restrict__ h1p, const _Float16* __restrict__ w2h,
    const float* __restrict__ b2, _Float16* __restrict__ h2p)
{
    __shared__ __align__(16) char smem[33280];   // w2l 32768 + b2l 512
    float* b2l = (float*)(smem + 32768);
    const int tid = threadIdx.x;
    const int wv = tid >> 6, lane = tid & 63;
    const int row16 = lane & 15, quad = lane >> 4;
    const int ptile = blockIdx.x;
    const int b = ptile >> 4;
    const int pim0 = (ptile & 15) << 8;

    if (tid < 128) b2l[tid] = b2[tid];
#pragma unroll
    for (int k = 0; k < 8; ++k) {
        const int c0 = k * 256 + wv * 64;
        ASYNC16(w2h + (size_t)(c0 + lane) * 8, smem + c0 * 16);
    }

    f32x4 acc[4][8];
#pragma unroll
    for (int pt = 0; pt < 4; ++pt)
#pragma unroll
        for (int ot = 0; ot < 8; ++ot) acc[pt][ot] = (f32x4){0.f, 0.f, 0.f, 0.f};

    const int pixbase = (b << 12) + pim0 + wv * 64;
    __syncthreads();

#pragma unroll
    for (int ks = 0; ks < 4; ++ks) {
        half8 bf[4], af[8];
#pragma unroll
        for (int pt = 0; pt < 4; ++pt)
            bf[pt] = *(const half8*)(h1p + ((size_t)(pixbase + pt * 16 + row16) << 7) + ks * 32 + quad * 8);
        const _Float16* wl = (const _Float16*)smem;
#pragma unroll
        for (int ot = 0; ot < 8; ++ot)
            af[ot] = *(const half8*)(wl + ((ks * 128 + ot * 16 + row16) << 5) + quad * 8);
#pragma unroll
        for (int ot = 0; ot < 8; ++ot)
#pragma unroll
            for (int pt = 0; pt < 4; ++pt)
                acc[pt][ot] = __builtin_amdgcn_mfma_f32_16x16x32_f16(af[ot], bf[pt], acc[pt][ot], 0, 0, 0);
    }

    // epilogue: C lane holds pixel=row16(-tile), oc=ot*16+quad*4+r
#pragma unroll
    for (int pt = 0; pt < 4; ++pt) {
        const int p = pim0 + wv * 64 + pt * 16 + row16;      // within-image pixel
        const int pp = ((p >> 6) + 1) * 66 + (p & 63) + 1;
#pragma unroll
        for (int ot = 0; ot < 8; ++ot) {
            const int oc0 = ot * 16 + quad * 4;
            half4 v;
#pragma unroll
            for (int r = 0; r < 4; ++r)
                v[r] = (_Float16)fmaxf(acc[pt][ot][r] + b2l[oc0 + r], 0.f);
            *(half4*)(h2p + H2P_IDX(b, oc0 >> 5, pp) + (oc0 & 31)) = v;
        }
    }
}

// ---------------------------------------------------------------------------
// RQS spline evaluation for one element, given its 23 params in prm[].
// ---------------------------------------------------------------------------
__device__ __forceinline__ void rqs_eval(const float* prm, float xv,
                                         float& yv_out, float& lad_out)
{
    const float xin = fminf(fmaxf(xv, -3.f), 3.f);

    float mw = prm[0], mh = prm[8];
#pragma unroll
    for (int j = 1; j < 8; ++j) { mw = fmaxf(mw, prm[j]); mh = fmaxf(mh, prm[8 + j]); }
    float ew[8], eh[8];
    float sw = 0.f, sh = 0.f;
#pragma unroll
    for (int j = 0; j < 8; ++j) {
        ew[j] = expf(prm[j] - mw);      sw += ew[j];
        eh[j] = expf(prm[8 + j] - mh);  sh += eh[j];
    }
    const float rw = 1.f / sw, rh = 1.f / sh;

    const float CONST_D = logf(expf(0.999f) - 1.f);

    float cumw = 0.f, cumh = 0.f;
    float cw_lo = -3.f, ch_lo = -3.f;
    float in_cw = 0.f, in_w = 1.f, in_ch = 0.f, in_h = 1.f, sd0 = 0.f, sd1 = 0.f;
#pragma unroll
    for (int i = 0; i < 8; ++i) {
        cumw += fmaf(0.992f, ew[i] * rw, 0.001f);
        cumh += fmaf(0.992f, eh[i] * rh, 0.001f);
        const float cw_hi = (i == 7) ? 3.f : fmaf(6.f, cumw, -3.f);
        const float ch_hi = (i == 7) ? 3.f : fmaf(6.f, cumh, -3.f);
        const bool sel = (xin >= cw_lo) && ((i == 7) || (xin < cw_hi));
        in_cw = sel ? cw_lo : in_cw;
        in_w  = sel ? (cw_hi - cw_lo) : in_w;
        in_ch = sel ? ch_lo : in_ch;
        in_h  = sel ? (ch_hi - ch_lo) : in_h;
        sd0   = sel ? ((i == 0) ? CONST_D : prm[16 + i - 1]) : sd0;
        sd1   = sel ? ((i == 7) ? CONST_D : prm[16 + i]) : sd1;
        cw_lo = cw_hi; ch_lo = ch_hi;
    }

    const float d0 = 0.001f + ((sd0 > 20.f) ? sd0 : log1pf(expf(sd0)));
    const float d1 = 0.001f + ((sd1 > 20.f) ? sd1 : log1pf(expf(sd1)));

    const float delta = in_h / in_w;
    const float theta = (xin - in_cw) / in_w;
    const float omt = 1.f - theta;
    const float tom = theta * omt;
    const float th2 = theta * theta;
    const float numer = in_h * (delta * th2 + d0 * tom);
    const float denom = delta + (d0 + d1 - 2.f * delta) * tom;
    float yv = in_ch + numer / denom;
    const float dnum = delta * delta * (d1 * th2 + 2.f * delta * tom + d0 * omt * omt);
    float lad = logf(dnum) - 2.f * logf(denom);

    const bool inside = (xv >= -3.f) && (xv <= 3.f);
    yv_out = inside ? yv : xv;
    lad_out = inside ? lad : 0.f;
}

// ---------------------------------------------------------------------------
// conv3 v4: round-4 K-loop (direct global->VGPR fragments, no staging, no
// K-loop barriers) + FULLY UNROLLED epilogue: acc[pt][ot] only ever indexed
// by compile-time constants => SROA keeps the accumulator in registers/AGPRs
// (rounds 3-5's 0.15-5.5 GB WRITE_SIZE was scratch spill caused by the
// runtime-indexed `#pragma unroll 1` epilogue loop).
// GEMM: M=pixels (tile 256), N=oc' 288 (2 cols x 144), K=1152 (9 taps x 128ci)
// WG = 256 thr (4 waves). Wave wv: pixels [wv*64,..+64) x 144 oc'
//   = 4 pix-tiles x 9 oc-tiles of 16x16x32 MFMA; acc = 144 regs.
// ---------------------------------------------------------------------------
__global__ __launch_bounds__(256, 2) void conv3_rqs_k(
    const _Float16* __restrict__ h2p, const _Float16* __restrict__ w3h,
    const float* __restrict__ b3, const float* __restrict__ x,
    float* __restrict__ y, float* __restrict__ ld_out)
{
    __shared__ __align__(16) float epi_smem[4 * 2304];   // 36864 B, epilogue only
    __shared__ float b3l[144];

    const int tid = threadIdx.x;
    const int wv = tid >> 6, lane = tid & 63;
    const int row16 = lane & 15, quad = lane >> 4;
    const int col = blockIdx.x;            // 0..1 -> oc' base col*144, channels col*6..+5
    const int ptile = blockIdx.y;
    const int b = ptile >> 4;
    const int pim0 = (ptile & 15) << 8;    // within-image pixel base (256-tile)
    const int h0 = pim0 >> 6;              // base row (multiple of 4)

    if (tid < 144) {
        const int c = tid / 24, j = tid % 24;
        b3l[tid] = (j < 23) ? b3[(col * 6 + c) * 23 + j] : 0.f;
    }

    f32x4 acc[4][9];
#pragma unroll
    for (int pt = 0; pt < 4; ++pt)
#pragma unroll
        for (int ot = 0; ot < 9; ++ot) acc[pt][ot] = (f32x4){0.f, 0.f, 0.f, 0.f};

    // B-frag lane (row16,quad): B[k=quad*8+j][n=row16] => pixel col, ci.
    // A-frag lane: A[m=row16][k=quad*8+j] => oc, ci.
    for (int t = 0; t < 9; ++t) {
        const int dy = t / 3 - 1, dx = t % 3 - 1;
        const int prow = h0 + wv + dy + 1;               // padded source row
        const int pbase = prow * 66 + dx + 1 + row16;
#pragma unroll
        for (int cc = 0; cc < 4; ++cc) {
            half8 bf[4], af[9];
#pragma unroll
            for (int pt = 0; pt < 4; ++pt)
                bf[pt] = *(const half8*)(h2p + H2P_IDX(b, cc, pbase + pt * 16) + quad * 8);
            const _Float16* gw = w3h + ((size_t)((t * 4 + cc) * 288 + col * 144) << 5);
#pragma unroll
            for (int ot = 0; ot < 9; ++ot)
                af[ot] = *(const half8*)(gw + ((ot * 16 + row16) << 5) + quad * 8);
#pragma unroll
            for (int ot = 0; ot < 9; ++ot)
#pragma unroll
                for (int pt = 0; pt < 4; ++pt)
                    acc[pt][ot] = __builtin_amdgcn_mfma_f32_16x16x32_f16(af[ot], bf[pt], acc[pt][ot], 0, 0, 0);
        }
    }

    __syncthreads();   // b3l visible; epi region about to be used

    // ---- epilogue: FULLY UNROLLED over pt (constant acc indices only) ----
    float* epi = epi_smem + wv * 2304;     // wave-private 16 pix x 144 oc'
    float lad_acc = 0.f;
#pragma unroll
    for (int pt = 0; pt < 4; ++pt) {
#pragma unroll
        for (int ot = 0; ot < 9; ++ot)
            *(f32x4*)(epi + row16 * 144 + ot * 16 + quad * 4) = acc[pt][ot];
        __syncthreads();
#pragma unroll 1
        for (int pass = 0; pass < 2; ++pass) {
            const int idx = pass * 64 + lane;
            if (idx < 96) {
                const int p16 = idx & 15, c = idx >> 4;       // c 0..5
                float prm[23];
#pragma unroll
                for (int j = 0; j < 23; ++j)
                    prm[j] = epi[p16 * 144 + c * 24 + j] + b3l[c * 24 + j];
                const int tpix = wv * 64 + pt * 16 + p16;
                const size_t xi = (((size_t)(b * 12 + col * 6 + c)) << 12) + (pim0 + tpix);
                const float xv = x[xi];
                float yv, lad;
                rqs_eval(prm, xv, yv, lad);
                y[xi] = yv;
                lad_acc += lad;
            }
        }
        __syncthreads();   // epi region reuse across pt
    }

#pragma unroll
    for (int off = 32; off > 0; off >>= 1) lad_acc += __shfl_down(lad_acc, off);
    if (lane == 0) atomicAdd(&ld_out[b], lad_acc);
}

// ---------------------------------------------------------------------------
extern "C" void kernel_launch(void* const* d_in, const int* in_sizes, int n_in,
                              void* d_out, int out_size, void* d_ws, size_t ws_size,
                              hipStream_t stream)
{
    const float* x      = (const float*)d_in[0];
    const float* logdet = (const float*)d_in[1];
    const float* cond   = (const float*)d_in[2];
    const float* w1     = (const float*)d_in[3];
    const float* b1     = (const float*)d_in[4];
    const float* w2     = (const float*)d_in[5];
    const float* b2     = (const float*)d_in[6];
    const float* w3     = (const float*)d_in[7];
    const float* b3     = (const float*)d_in[8];

    char* ws = (char*)d_ws;
    _Float16* h1p = (_Float16*)ws;                       // 33,554,432 B  [b][pix][128oc]
    _Float16* h2p = (_Float16*)(ws + 33554432);          // 35,684,352 B
    float*    w1t = (float*)(ws + 69238784);             // 73,728 B
    _Float16* w2h = (_Float16*)(ws + 69312512);          // 32,768 B
    _Float16* w3h = (_Float16*)(ws + 69345280);          // 663,552 B (end ~70 MB)

    float* y      = (float*)d_out;                       // NY floats
    float* ld_out = y + NY;                              // 32 floats

    prep_k<<<1296, 256, 0, stream>>>(w1, w2, w3, w1t, w2h, w3h, logdet, ld_out);
    zring_k<<<520, 256, 0, stream>>>(h2p);
    conv1_k<<<dim3(4, 64, 32), 64, 0, stream>>>(x, cond, w1t, b1, h1p);
    conv2_k<<<512, 256, 0, stream>>>(h1p, w2h, b2, h2p);
    conv3_rqs_k<<<dim3(2, 512), 256, 0, stream>>>(h2p, w3h, b3, x, y, ld_out);
}

// Round 7
// 249.627 us; speedup vs baseline: 4.0840x; 1.6017x over previous
//
#include <hip/hip_runtime.h>
#include <math.h>

// B=32, C=12, H=64, W=64, hidden=128, cond_c=4, out_spline=276 (pad->288=12*24)
// NUM_BINS=8, TAIL=3.0, MBW=MBH=MD=0.001

#define NPIX 4096
#define NY   1572864

typedef _Float16 half8 __attribute__((ext_vector_type(8)));
typedef _Float16 half4 __attribute__((ext_vector_type(4)));
typedef float f32x4 __attribute__((ext_vector_type(4)));

// async global->LDS, 16B per lane: HW writes LDS base + lane*16; lds base wave-uniform
#define ASYNC16(gsrc, ldst) \
  __builtin_amdgcn_global_load_lds((const __attribute__((address_space(1))) unsigned int*)(gsrc), \
                                   (__attribute__((address_space(3))) unsigned int*)(ldst), 16, 0, 0)

// h2p layout: [b][cc=ci/32][pp=66*66][ci%32] fp16, halo ring of zeros
#define H2P_PLANE 4356            // 66*66
#define H2P_IDX(b, cc, pp) ((((size_t)(b) * 4 + (cc)) * H2P_PLANE + (pp)) << 5)
// xh layout: [b][pp=66*66][32] fp16 (ci<12 x, 12..15 cond, >=16 zero; halo zero)
#define XH_IDX(b, pp) (((size_t)(b) * H2P_PLANE + (pp)) << 5)

// ---------------------------------------------------------------------------
// prep: weight packs + logdet init
//   w1 (128,16,3,3)  -> w1h[(t*128+oc)*32 + k]   k=ci<16 real, k>=16 zero   fp16
//   w2 (128,128,1,1) -> w2h[(ks*128+oc)*32 + km]  (ci=ks*32+km)             fp16
//   w3 (276,128,3,3) -> w3h[((t*4+cc)*288 + oc')*32 + cim]                  fp16
//                       oc' = c*24 + j (j<23 real, j=23 zero pad)
// ---------------------------------------------------------------------------
__global__ __launch_bounds__(256) void prep_k(
    const float* __restrict__ w1, const float* __restrict__ w2,
    const float* __restrict__ w3, _Float16* __restrict__ w1h,
    _Float16* __restrict__ w2h, _Float16* __restrict__ w3h,
    const float* __restrict__ logdet, float* __restrict__ ld_out)
{
    const int i = blockIdx.x * 256 + threadIdx.x;   // < 331776
    if (i < 36864) {                     // w1h
        int k = i & 31, oc = (i >> 5) & 127, t = i >> 12;
        w1h[i] = (_Float16)((k < 16) ? w1[(oc * 16 + k) * 9 + t] : 0.f);
    }
    if (i < 16384) {                     // w2h
        int km = i & 31, oc = (i >> 5) & 127, ks = i >> 12;
        w2h[i] = (_Float16)w2[oc * 128 + ks * 32 + km];
    }
    {   // w3h: flat i = ((t*4+cc)*288 + oc)*32 + cim
        int cim = i & 31;
        int oc = (i >> 5) % 288;
        int tc = i / (288 * 32);        // 0..35
        int t = tc >> 2, cc = tc & 3;
        int c = oc / 24, j = oc % 24;
        int ci = cc * 32 + cim;
        float v = (j < 23) ? w3[((c * 23 + j) * 128 + ci) * 9 + t] : 0.f;
        w3h[i] = (_Float16)v;
    }
    if (i < 32) ld_out[i] = logdet[i];
}

// ---------------------------------------------------------------------------
// xh: pack x(12ch fp32) + cond(4ch fp32) into halo-padded fp16 [b][66*66][32]
// one thread per (b,pp): writes 64B; halo and ci>=16 are zeros.
// ---------------------------------------------------------------------------
__global__ __launch_bounds__(256) void xh_k(
    const float* __restrict__ x, const float* __restrict__ cond,
    _Float16* __restrict__ xh)
{
    const int i = blockIdx.x * 256 + threadIdx.x;
    if (i >= 139392) return;                       // 32*4356
    const int b = i / H2P_PLANE, pp = i % H2P_PLANE;
    const int pr = pp / 66, pc = pp % 66;
    const bool interior = (pr >= 1) && (pr <= 64) && (pc >= 1) && (pc <= 64);
    _Float16 v[32];
#pragma unroll
    for (int ci = 0; ci < 32; ++ci) v[ci] = (_Float16)0.f;
    if (interior) {
        const int p = (pr - 1) * 64 + (pc - 1);
#pragma unroll
        for (int ci = 0; ci < 12; ++ci)
            v[ci] = (_Float16)x[((size_t)(b * 12 + ci) << 12) + p];
#pragma unroll
        for (int ci = 0; ci < 4; ++ci)
            v[12 + ci] = (_Float16)cond[((size_t)(b * 4 + ci) << 12) + p];
    }
    _Float16* dst = xh + ((size_t)i << 5);
#pragma unroll
    for (int q = 0; q < 4; ++q) *(f32x4*)(dst + q * 8) = *(f32x4*)(v + q * 8);
}

// ---------------------------------------------------------------------------
// zero the halo ring of h2p (260 border pixels per (b,cc) plane)
// ---------------------------------------------------------------------------
__global__ __launch_bounds__(256) void zring_k(_Float16* __restrict__ h2p)
{
    const int i = blockIdx.x * 256 + threadIdx.x;
    if (i >= 133120) return;
    const int q = i & 3;
    const int rest = i >> 2;
    const int r = rest % 260;
    const int cc = (rest / 260) & 3;
    const int b = rest / 1040;
    int pp;
    if (r < 66)       pp = r;
    else if (r < 132) pp = 65 * 66 + (r - 66);
    else if (r < 196) pp = (r - 131) * 66;
    else              pp = (r - 195) * 66 + 65;
    f32x4 z = {0.f, 0.f, 0.f, 0.f};
    *(f32x4*)(h2p + H2P_IDX(b, cc, pp) + q * 8) = z;
}

// ---------------------------------------------------------------------------
// conv1 as implicit-GEMM MFMA: M=pixels, N=128 oc, K=9 taps x 32 (16 real ci).
// Entire w1h (72 KB) staged in LDS once; ZERO K-loop barriers after that.
// Block 256 thr (4 waves) x 256 pix; wave = 64 pix x 128 oc, acc 4x8=128 regs.
// bf direct global from halo-padded xh (no border masks). bias+relu epilogue
// -> h1p [b][pix][128oc] fp16.
// ---------------------------------------------------------------------------
__global__ __launch_bounds__(256, 2) void conv1_k(
    const _Float16* __restrict__ xh, const _Float16* __restrict__ w1h,
    const float* __restrict__ b1, _Float16* __restrict__ h1p)
{
    __shared__ __align__(16) char smem[73728];     // all 9 taps x 128 oc x 32 k
    const int tid = threadIdx.x;
    const int wv = tid >> 6, lane = tid & 63;
    const int row16 = lane & 15, quad = lane >> 4;
    const int ptile = blockIdx.x;
    const int b = ptile >> 4;
    const int pim0 = (ptile & 15) << 8;
    const int h0 = pim0 >> 6;

#pragma unroll
    for (int k = 0; k < 18; ++k)                   // 4608 16B chunks
        ASYNC16(w1h + (size_t)(k * 256 + tid) * 8, smem + (k * 256 + wv * 64) * 16);

    f32x4 acc[4][8];
#pragma unroll
    for (int pt = 0; pt < 4; ++pt)
#pragma unroll
        for (int ot = 0; ot < 8; ++ot) acc[pt][ot] = (f32x4){0.f, 0.f, 0.f, 0.f};

    __syncthreads();
    const _Float16* wl = (const _Float16*)smem;

    for (int t = 0; t < 9; ++t) {
        const int dy = t / 3, dx = t % 3;
        const int pbase = (h0 + wv + dy) * 66 + dx + row16;
        half8 bf[4], af[8];
#pragma unroll
        for (int pt = 0; pt < 4; ++pt)
            bf[pt] = *(const half8*)(xh + XH_IDX(b, pbase + pt * 16) + quad * 8);
#pragma unroll
        for (int ot = 0; ot < 8; ++ot)
            af[ot] = *(const half8*)(wl + ((t * 128 + ot * 16 + row16) << 5) + quad * 8);
#pragma unroll
        for (int ot = 0; ot < 8; ++ot)
#pragma unroll
            for (int pt = 0; pt < 4; ++pt)
                acc[pt][ot] = __builtin_amdgcn_mfma_f32_16x16x32_f16(af[ot], bf[pt], acc[pt][ot], 0, 0, 0);
    }

    // epilogue: lane holds pixel=row16(tile), oc=ot*16+quad*4+r
    f32x4 bias[8];
#pragma unroll
    for (int ot = 0; ot < 8; ++ot) bias[ot] = *(const f32x4*)(b1 + ot * 16 + quad * 4);
#pragma unroll
    for (int pt = 0; pt < 4; ++pt) {
        const size_t pbase = ((size_t)((b << 12) + pim0 + wv * 64 + pt * 16 + row16)) << 7;
#pragma unroll
        for (int ot = 0; ot < 8; ++ot) {
            half4 v;
#pragma unroll
            for (int r = 0; r < 4; ++r)
                v[r] = (_Float16)fmaxf(acc[pt][ot][r] + bias[ot][r], 0.f);
            *(half4*)(h1p + pbase + ot * 16 + quad * 4) = v;
        }
    }
}

// ---------------------------------------------------------------------------
// conv2 as MFMA GEMM: M=pixels, N=128 oc, K=128. Whole w2 (32 KB fp16) staged
// in LDS once. Block = 256 thr (4 waves) x 256 pixels; wave = 64 pix x 128 oc.
// bias+relu epilogue, direct h2p stores.
// ---------------------------------------------------------------------------
__global__ __launch_bounds__(256, 2) void conv2_k(
    const _Float16* __restrict__ h1p, const _Float16* __restrict__ w2h,
    const float* __restrict__ b2, _Float16* __restrict__ h2p)
{
    __shared__ __align__(16) char smem[33280];   // w2l 32768 + b2l 512
    float* b2l = (float*)(smem + 32768);
    const int tid = threadIdx.x;
    const int wv = tid >> 6, lane = tid & 63;
    const int row16 = lane & 15, quad = lane >> 4;
    const int ptile = blockIdx.x;
    const int b = ptile >> 4;
    const int pim0 = (ptile & 15) << 8;

    if (tid < 128) b2l[tid] = b2[tid];
#pragma unroll
    for (int k = 0; k < 8; ++k) {
        const int c0 = k * 256 + wv * 64;
        ASYNC16(w2h + (size_t)(c0 + lane) * 8, smem + c0 * 16);
    }

    f32x4 acc[4][8];
#pragma unroll
    for (int pt = 0; pt < 4; ++pt)
#pragma unroll
        for (int ot = 0; ot < 8; ++ot) acc[pt][ot] = (f32x4){0.f, 0.f, 0.f, 0.f};

    const int pixbase = (b << 12) + pim0 + wv * 64;
    __syncthreads();

#pragma unroll
    for (int ks = 0; ks < 4; ++ks) {
        half8 bf[4], af[8];
#pragma unroll
        for (int pt = 0; pt < 4; ++pt)
            bf[pt] = *(const half8*)(h1p + ((size_t)(pixbase + pt * 16 + row16) << 7) + ks * 32 + quad * 8);
        const _Float16* wl = (const _Float16*)smem;
#pragma unroll
        for (int ot = 0; ot < 8; ++ot)
            af[ot] = *(const half8*)(wl + ((ks * 128 + ot * 16 + row16) << 5) + quad * 8);
#pragma unroll
        for (int ot = 0; ot < 8; ++ot)
#pragma unroll
            for (int pt = 0; pt < 4; ++pt)
                acc[pt][ot] = __builtin_amdgcn_mfma_f32_16x16x32_f16(af[ot], bf[pt], acc[pt][ot], 0, 0, 0);
    }

    // epilogue: lane holds pixel=row16(tile), oc=ot*16+quad*4+r
#pragma unroll
    for (int pt = 0; pt < 4; ++pt) {
        const int p = pim0 + wv * 64 + pt * 16 + row16;      // within-image pixel
        const int pp = ((p >> 6) + 1) * 66 + (p & 63) + 1;
#pragma unroll
        for (int ot = 0; ot < 8; ++ot) {
            const int oc0 = ot * 16 + quad * 4;
            half4 v;
#pragma unroll
            for (int r = 0; r < 4; ++r)
                v[r] = (_Float16)fmaxf(acc[pt][ot][r] + b2l[oc0 + r], 0.f);
            *(half4*)(h2p + H2P_IDX(b, oc0 >> 5, pp) + (oc0 & 31)) = v;
        }
    }
}

// ---------------------------------------------------------------------------
// RQS spline evaluation for one element, given its 23 params in prm[].
// ---------------------------------------------------------------------------
__device__ __forceinline__ void rqs_eval(const float* prm, float xv,
                                         float& yv_out, float& lad_out)
{
    const float xin = fminf(fmaxf(xv, -3.f), 3.f);

    float mw = prm[0], mh = prm[8];
#pragma unroll
    for (int j = 1; j < 8; ++j) { mw = fmaxf(mw, prm[j]); mh = fmaxf(mh, prm[8 + j]); }
    float ew[8], eh[8];
    float sw = 0.f, sh = 0.f;
#pragma unroll
    for (int j = 0; j < 8; ++j) {
        ew[j] = expf(prm[j] - mw);      sw += ew[j];
        eh[j] = expf(prm[8 + j] - mh);  sh += eh[j];
    }
    const float rw = 1.f / sw, rh = 1.f / sh;

    const float CONST_D = logf(expf(0.999f) - 1.f);

    float cumw = 0.f, cumh = 0.f;
    float cw_lo = -3.f, ch_lo = -3.f;
    float in_cw = 0.f, in_w = 1.f, in_ch = 0.f, in_h = 1.f, sd0 = 0.f, sd1 = 0.f;
#pragma unroll
    for (int i = 0; i < 8; ++i) {
        cumw += fmaf(0.992f, ew[i] * rw, 0.001f);
        cumh += fmaf(0.992f, eh[i] * rh, 0.001f);
        const float cw_hi = (i == 7) ? 3.f : fmaf(6.f, cumw, -3.f);
        const float ch_hi = (i == 7) ? 3.f : fmaf(6.f, cumh, -3.f);
        const bool sel = (xin >= cw_lo) && ((i == 7) || (xin < cw_hi));
        in_cw = sel ? cw_lo : in_cw;
        in_w  = sel ? (cw_hi - cw_lo) : in_w;
        in_ch = sel ? ch_lo : in_ch;
        in_h  = sel ? (ch_hi - ch_lo) : in_h;
        sd0   = sel ? ((i == 0) ? CONST_D : prm[16 + i - 1]) : sd0;
        sd1   = sel ? ((i == 7) ? CONST_D : prm[16 + i]) : sd1;
        cw_lo = cw_hi; ch_lo = ch_hi;
    }

    const float d0 = 0.001f + ((sd0 > 20.f) ? sd0 : log1pf(expf(sd0)));
    const float d1 = 0.001f + ((sd1 > 20.f) ? sd1 : log1pf(expf(sd1)));

    const float delta = in_h / in_w;
    const float theta = (xin - in_cw) / in_w;
    const float omt = 1.f - theta;
    const float tom = theta * omt;
    const float th2 = theta * theta;
    const float numer = in_h * (delta * th2 + d0 * tom);
    const float denom = delta + (d0 + d1 - 2.f * delta) * tom;
    float yv = in_ch + numer / denom;
    const float dnum = delta * delta * (d1 * th2 + 2.f * delta * tom + d0 * omt * omt);
    float lad = logf(dnum) - 2.f * logf(denom);

    const bool inside = (xv >= -3.f) && (xv <= 3.f);
    yv_out = inside ? yv : xv;
    lad_out = inside ? lad : 0.f;
}

// ---------------------------------------------------------------------------
// conv3 v5: K-loop with per-tap LDS weight staging (36 KB double-buffered,
// shared by all 4 waves; af latency = ds_read not L2), bf direct global->VGPR
// from halo-padded h2p. 9 barriers total. Epilogue FULLY UNROLLED (constant
// acc indices — the round-3/5 spill trap) with +4 pad on epi row stride to
// kill bank conflicts.
// GEMM: M=pixels (tile 256), N=oc' 288 (2 cols x 144), K=1152 (9 taps x 128ci)
// ---------------------------------------------------------------------------
__global__ __launch_bounds__(256, 2) void conv3_rqs_k(
    const _Float16* __restrict__ h2p, const _Float16* __restrict__ w3h,
    const float* __restrict__ b3, const float* __restrict__ x,
    float* __restrict__ y, float* __restrict__ ld_out)
{
    __shared__ __align__(16) char smem[74304];
    // wt0 [0,36864)  wt1 [36864,73728)  b3l [73728,74304)
    // epilogue overlay: epi 4 waves x 2368 floats = [0,37888)
    float* b3l = (float*)(smem + 73728);

    const int tid = threadIdx.x;
    const int wv = tid >> 6, lane = tid & 63;
    const int row16 = lane & 15, quad = lane >> 4;
    const int col = blockIdx.x;            // 0..1 -> oc' base col*144, ch col*6..+5
    const int ptile = blockIdx.y;
    const int b = ptile >> 4;
    const int pim0 = (ptile & 15) << 8;
    const int h0 = pim0 >> 6;

    if (tid < 144) {
        const int c = tid / 24, j = tid % 24;
        b3l[tid] = (j < 23) ? b3[(col * 6 + c) * 23 + j] : 0.f;
    }

    // per-thread global element offsets for weight staging (9 chunks of 16B)
    // chunk c = k*256+tid -> cc = c/576, rem = c%576; per (t,cc) region is
    // 9216 B contiguous at ((t*4+cc)*288 + col*144)*32 elems.
    int eoff[9];
#pragma unroll
    for (int k = 0; k < 9; ++k) {
        const int chunk = k * 256 + tid;
        const int cc = chunk / 576, rem = chunk - cc * 576;
        eoff[k] = cc * 9216 + col * 4608 + rem * 8;
    }
    auto stage_wt = [&](int t, int buf) {
        const _Float16* g = w3h + (size_t)t * 36864;
        char* wb = smem + buf * 36864;
#pragma unroll
        for (int k = 0; k < 9; ++k)
            ASYNC16(g + eoff[k], wb + (k * 256 + wv * 64) * 16);
    };

    f32x4 acc[4][9];
#pragma unroll
    for (int pt = 0; pt < 4; ++pt)
#pragma unroll
        for (int ot = 0; ot < 9; ++ot) acc[pt][ot] = (f32x4){0.f, 0.f, 0.f, 0.f};

    stage_wt(0, 0);

    for (int t = 0; t < 9; ++t) {
        __syncthreads();                   // buf t&1 staged; buf (t+1)&1 free
        if (t < 8) stage_wt(t + 1, (t + 1) & 1);
        const _Float16* wt = (const _Float16*)(smem + (t & 1) * 36864);
        const int dy = t / 3, dx = t % 3;
        const int pbase = (h0 + wv + dy) * 66 + dx + row16;
#pragma unroll
        for (int cc = 0; cc < 4; ++cc) {
            half8 bf[4], af[9];
#pragma unroll
            for (int pt = 0; pt < 4; ++pt)
                bf[pt] = *(const half8*)(h2p + H2P_IDX(b, cc, pbase + pt * 16) + quad * 8);
#pragma unroll
            for (int ot = 0; ot < 9; ++ot)
                af[ot] = *(const half8*)(wt + cc * 4608 + ((ot * 16 + row16) << 5) + quad * 8);
#pragma unroll
            for (int ot = 0; ot < 9; ++ot)
#pragma unroll
                for (int pt = 0; pt < 4; ++pt)
                    acc[pt][ot] = __builtin_amdgcn_mfma_f32_16x16x32_f16(af[ot], bf[pt], acc[pt][ot], 0, 0, 0);
        }
    }

    __syncthreads();   // K-loop LDS reads done; epi overlay safe

    // ---- epilogue: FULLY UNROLLED over pt (constant acc indices only) ----
    float* epi = (float*)smem + wv * 2368;     // 16 pix x 148-stride floats
    float lad_acc = 0.f;
#pragma unroll
    for (int pt = 0; pt < 4; ++pt) {
#pragma unroll
        for (int ot = 0; ot < 9; ++ot)
            *(f32x4*)(epi + row16 * 148 + ot * 16 + quad * 4) = acc[pt][ot];
        __syncthreads();
#pragma unroll 1
        for (int pass = 0; pass < 2; ++pass) {
            const int idx = pass * 64 + lane;
            if (idx < 96) {
                const int p16 = idx & 15, c = idx >> 4;       // c 0..5
                float prm[23];
#pragma unroll
                for (int j = 0; j < 23; ++j)
                    prm[j] = epi[p16 * 148 + c * 24 + j] + b3l[c * 24 + j];
                const int tpix = wv * 64 + pt * 16 + p16;
                const size_t xi = (((size_t)(b * 12 + col * 6 + c)) << 12) + (pim0 + tpix);
                const float xv = x[xi];
                float yv, lad;
                rqs_eval(prm, xv, yv, lad);
                y[xi] = yv;
                lad_acc += lad;
            }
        }
        __syncthreads();   // epi region reuse across pt
    }

#pragma unroll
    for (int off = 32; off > 0; off >>= 1) lad_acc += __shfl_down(lad_acc, off);
    if (lane == 0) atomicAdd(&ld_out[b], lad_acc);
}

// ---------------------------------------------------------------------------
extern "C" void kernel_launch(void* const* d_in, const int* in_sizes, int n_in,
                              void* d_out, int out_size, void* d_ws, size_t ws_size,
                              hipStream_t stream)
{
    const float* x      = (const float*)d_in[0];
    const float* logdet = (const float*)d_in[1];
    const float* cond   = (const float*)d_in[2];
    const float* w1     = (const float*)d_in[3];
    const float* b1     = (const float*)d_in[4];
    const float* w2     = (const float*)d_in[5];
    const float* b2     = (const float*)d_in[6];
    const float* w3     = (const float*)d_in[7];
    const float* b3     = (const float*)d_in[8];

    char* ws = (char*)d_ws;
    _Float16* h1p = (_Float16*)ws;                       // 33,554,432 B  [b][pix][128oc]
    _Float16* h2p = (_Float16*)(ws + 33554432);          // 35,684,352 B
    _Float16* xh  = (_Float16*)(ws + 33554432);          // 8,921,088 B — ALIASES h2p
                                                         // (consumed by conv1 before
                                                         //  zring/conv2 write h2p)
    _Float16* w1h = (_Float16*)(ws + 69238784);          // 73,728 B
    _Float16* w2h = (_Float16*)(ws + 69312512);          // 32,768 B
    _Float16* w3h = (_Float16*)(ws + 69345280);          // 663,552 B (end ~70 MB)

    float* y      = (float*)d_out;                       // NY floats
    float* ld_out = y + NY;                              // 32 floats

    prep_k<<<1296, 256, 0, stream>>>(w1, w2, w3, w1h, w2h, w3h, logdet, ld_out);
    xh_k<<<545, 256, 0, stream>>>(x, cond, xh);
    conv1_k<<<512, 256, 0, stream>>>(xh, w1h, b1, h1p);
    zring_k<<<520, 256, 0, stream>>>(h2p);
    conv2_k<<<512, 256, 0, stream>>>(h1p, w2h, b2, h2p);
    conv3_rqs_k<<<dim3(2, 512), 256, 0, stream>>>(h2p, w3h, b3, x, y, ld_out);
}

// Round 8
// 240.031 us; speedup vs baseline: 4.2473x; 1.0400x over previous
//
#include <hip/hip_runtime.h>
#include <math.h>

// B=32, C=12, H=64, W=64, hidden=128, cond_c=4, out_spline=276 (pad->288=12*24)
// NUM_BINS=8, TAIL=3.0, MBW=MBH=MD=0.001

#define NPIX 4096
#define NY   1572864

typedef _Float16 half8 __attribute__((ext_vector_type(8)));
typedef _Float16 half4 __attribute__((ext_vector_type(4)));
typedef float f32x4 __attribute__((ext_vector_type(4)));

// async global->LDS, 16B per lane: HW writes LDS base + lane*16; lds base wave-uniform
#define ASYNC16(gsrc, ldst) \
  __builtin_amdgcn_global_load_lds((const __attribute__((address_space(1))) unsigned int*)(gsrc), \
                                   (__attribute__((address_space(3))) unsigned int*)(ldst), 16, 0, 0)

// h2p layout: [b][cc=ci/32][pp=66*66][ci%32] fp16, halo ring of zeros
#define H2P_PLANE 4356            // 66*66
#define H2P_IDX(b, cc, pp) ((((size_t)(b) * 4 + (cc)) * H2P_PLANE + (pp)) << 5)
// xh layout: [b][pp=66*66][32] fp16 (ci<12 x, 12..15 cond, >=16 zero; halo zero)
#define XH_IDX(b, pp) (((size_t)(b) * H2P_PLANE + (pp)) << 5)

// ---------------------------------------------------------------------------
// prep: weight packs + logdet init
//   w1 (128,16,3,3)  -> w1h[(t*128+oc)*32 + k]   k=ci<16 real, k>=16 zero   fp16
//   w2 (128,128,1,1) -> w2h[(ks*128+oc)*32 + km]  (ci=ks*32+km)             fp16
//   w3 (276,128,3,3) -> w3h[((t*4+cc)*288 + oc')*32 + cim]                  fp16
//                       oc' = c*24 + j (j<23 real, j=23 zero pad)
// ---------------------------------------------------------------------------
__global__ __launch_bounds__(256) void prep_k(
    const float* __restrict__ w1, const float* __restrict__ w2,
    const float* __restrict__ w3, _Float16* __restrict__ w1h,
    _Float16* __restrict__ w2h, _Float16* __restrict__ w3h,
    const float* __restrict__ logdet, float* __restrict__ ld_out)
{
    const int i = blockIdx.x * 256 + threadIdx.x;   // < 331776
    if (i < 36864) {                     // w1h
        int k = i & 31, oc = (i >> 5) & 127, t = i >> 12;
        w1h[i] = (_Float16)((k < 16) ? w1[(oc * 16 + k) * 9 + t] : 0.f);
    }
    if (i < 16384) {                     // w2h
        int km = i & 31, oc = (i >> 5) & 127, ks = i >> 12;
        w2h[i] = (_Float16)w2[oc * 128 + ks * 32 + km];
    }
    {   // w3h: flat i = ((t*4+cc)*288 + oc)*32 + cim
        int cim = i & 31;
        int oc = (i >> 5) % 288;
        int tc = i / (288 * 32);        // 0..35
        int t = tc >> 2, cc = tc & 3;
        int c = oc / 24, j = oc % 24;
        int ci = cc * 32 + cim;
        float v = (j < 23) ? w3[((c * 23 + j) * 128 + ci) * 9 + t] : 0.f;
        w3h[i] = (_Float16)v;
    }
    if (i < 32) ld_out[i] = logdet[i];
}

// ---------------------------------------------------------------------------
// xh: pack x(12ch fp32) + cond(4ch fp32) into halo-padded fp16 [b][66*66][32]
// ---------------------------------------------------------------------------
__global__ __launch_bounds__(256) void xh_k(
    const float* __restrict__ x, const float* __restrict__ cond,
    _Float16* __restrict__ xh)
{
    const int i = blockIdx.x * 256 + threadIdx.x;
    if (i >= 139392) return;                       // 32*4356
    const int b = i / H2P_PLANE, pp = i % H2P_PLANE;
    const int pr = pp / 66, pc = pp % 66;
    const bool interior = (pr >= 1) && (pr <= 64) && (pc >= 1) && (pc <= 64);
    _Float16 v[32];
#pragma unroll
    for (int ci = 0; ci < 32; ++ci) v[ci] = (_Float16)0.f;
    if (interior) {
        const int p = (pr - 1) * 64 + (pc - 1);
#pragma unroll
        for (int ci = 0; ci < 12; ++ci)
            v[ci] = (_Float16)x[((size_t)(b * 12 + ci) << 12) + p];
#pragma unroll
        for (int ci = 0; ci < 4; ++ci)
            v[12 + ci] = (_Float16)cond[((size_t)(b * 4 + ci) << 12) + p];
    }
    _Float16* dst = xh + ((size_t)i << 5);
#pragma unroll
    for (int q = 0; q < 4; ++q) *(f32x4*)(dst + q * 8) = *(f32x4*)(v + q * 8);
}

// ---------------------------------------------------------------------------
// zero the halo ring of h2p (260 border pixels per (b,cc) plane)
// ---------------------------------------------------------------------------
__global__ __launch_bounds__(256) void zring_k(_Float16* __restrict__ h2p)
{
    const int i = blockIdx.x * 256 + threadIdx.x;
    if (i >= 133120) return;
    const int q = i & 3;
    const int rest = i >> 2;
    const int r = rest % 260;
    const int cc = (rest / 260) & 3;
    const int b = rest / 1040;
    int pp;
    if (r < 66)       pp = r;
    else if (r < 132) pp = 65 * 66 + (r - 66);
    else if (r < 196) pp = (r - 131) * 66;
    else              pp = (r - 195) * 66 + 65;
    f32x4 z = {0.f, 0.f, 0.f, 0.f};
    *(f32x4*)(h2p + H2P_IDX(b, cc, pp) + q * 8) = z;
}

// ---------------------------------------------------------------------------
// conv1 as implicit-GEMM MFMA: M=pixels, N=128 oc, K=9 taps x 32 (16 real ci).
// Entire w1h (72 KB) staged in LDS once; zero K-loop barriers after that.
// ---------------------------------------------------------------------------
__global__ __launch_bounds__(256, 2) void conv1_k(
    const _Float16* __restrict__ xh, const _Float16* __restrict__ w1h,
    const float* __restrict__ b1, _Float16* __restrict__ h1p)
{
    __shared__ __align__(16) char smem[73728];     // all 9 taps x 128 oc x 32 k
    const int tid = threadIdx.x;
    const int wv = tid >> 6, lane = tid & 63;
    const int row16 = lane & 15, quad = lane >> 4;
    const int ptile = blockIdx.x;
    const int b = ptile >> 4;
    const int pim0 = (ptile & 15) << 8;
    const int h0 = pim0 >> 6;

#pragma unroll
    for (int k = 0; k < 18; ++k)                   // 4608 16B chunks
        ASYNC16(w1h + (size_t)(k * 256 + tid) * 8, smem + (k * 256 + wv * 64) * 16);

    f32x4 acc[4][8];
#pragma unroll
    for (int pt = 0; pt < 4; ++pt)
#pragma unroll
        for (int ot = 0; ot < 8; ++ot) acc[pt][ot] = (f32x4){0.f, 0.f, 0.f, 0.f};

    __syncthreads();
    const _Float16* wl = (const _Float16*)smem;

    for (int t = 0; t < 9; ++t) {
        const int dy = t / 3, dx = t % 3;
        const int pbase = (h0 + wv + dy) * 66 + dx + row16;
        half8 bf[4], af[8];
#pragma unroll
        for (int pt = 0; pt < 4; ++pt)
            bf[pt] = *(const half8*)(xh + XH_IDX(b, pbase + pt * 16) + quad * 8);
#pragma unroll
        for (int ot = 0; ot < 8; ++ot)
            af[ot] = *(const half8*)(wl + ((t * 128 + ot * 16 + row16) << 5) + quad * 8);
#pragma unroll
        for (int ot = 0; ot < 8; ++ot)
#pragma unroll
            for (int pt = 0; pt < 4; ++pt)
                acc[pt][ot] = __builtin_amdgcn_mfma_f32_16x16x32_f16(af[ot], bf[pt], acc[pt][ot], 0, 0, 0);
    }

    f32x4 bias[8];
#pragma unroll
    for (int ot = 0; ot < 8; ++ot) bias[ot] = *(const f32x4*)(b1 + ot * 16 + quad * 4);
#pragma unroll
    for (int pt = 0; pt < 4; ++pt) {
        const size_t pbase = ((size_t)((b << 12) + pim0 + wv * 64 + pt * 16 + row16)) << 7;
#pragma unroll
        for (int ot = 0; ot < 8; ++ot) {
            half4 v;
#pragma unroll
            for (int r = 0; r < 4; ++r)
                v[r] = (_Float16)fmaxf(acc[pt][ot][r] + bias[ot][r], 0.f);
            *(half4*)(h1p + pbase + ot * 16 + quad * 4) = v;
        }
    }
}

// ---------------------------------------------------------------------------
// conv2 as MFMA GEMM: M=pixels, N=128 oc, K=128. Whole w2 (32 KB fp16) in LDS.
// ---------------------------------------------------------------------------
__global__ __launch_bounds__(256, 2) void conv2_k(
    const _Float16* __restrict__ h1p, const _Float16* __restrict__ w2h,
    const float* __restrict__ b2, _Float16* __restrict__ h2p)
{
    __shared__ __align__(16) char smem[33280];   // w2l 32768 + b2l 512
    float* b2l = (float*)(smem + 32768);
    const int tid = threadIdx.x;
    const int wv = tid >> 6, lane = tid & 63;
    const int row16 = lane & 15, quad = lane >> 4;
    const int ptile = blockIdx.x;
    const int b = ptile >> 4;
    const int pim0 = (ptile & 15) << 8;

    if (tid < 128) b2l[tid] = b2[tid];
#pragma unroll
    for (int k = 0; k < 8; ++k) {
        const int c0 = k * 256 + wv * 64;
        ASYNC16(w2h + (size_t)(c0 + lane) * 8, smem + c0 * 16);
    }

    f32x4 acc[4][8];
#pragma unroll
    for (int pt = 0; pt < 4; ++pt)
#pragma unroll
        for (int ot = 0; ot < 8; ++ot) acc[pt][ot] = (f32x4){0.f, 0.f, 0.f, 0.f};

    const int pixbase = (b << 12) + pim0 + wv * 64;
    __syncthreads();

#pragma unroll
    for (int ks = 0; ks < 4; ++ks) {
        half8 bf[4], af[8];
#pragma unroll
        for (int pt = 0; pt < 4; ++pt)
            bf[pt] = *(const half8*)(h1p + ((size_t)(pixbase + pt * 16 + row16) << 7) + ks * 32 + quad * 8);
        const _Float16* wl = (const _Float16*)smem;
#pragma unroll
        for (int ot = 0; ot < 8; ++ot)
            af[ot] = *(const half8*)(wl + ((ks * 128 + ot * 16 + row16) << 5) + quad * 8);
#pragma unroll
        for (int ot = 0; ot < 8; ++ot)
#pragma unroll
            for (int pt = 0; pt < 4; ++pt)
                acc[pt][ot] = __builtin_amdgcn_mfma_f32_16x16x32_f16(af[ot], bf[pt], acc[pt][ot], 0, 0, 0);
    }

#pragma unroll
    for (int pt = 0; pt < 4; ++pt) {
        const int p = pim0 + wv * 64 + pt * 16 + row16;      // within-image pixel
        const int pp = ((p >> 6) + 1) * 66 + (p & 63) + 1;
#pragma unroll
        for (int ot = 0; ot < 8; ++ot) {
            const int oc0 = ot * 16 + quad * 4;
            half4 v;
#pragma unroll
            for (int r = 0; r < 4; ++r)
                v[r] = (_Float16)fmaxf(acc[pt][ot][r] + b2l[oc0 + r], 0.f);
            *(half4*)(h2p + H2P_IDX(b, oc0 >> 5, pp) + (oc0 & 31)) = v;
        }
    }
}

// ---------------------------------------------------------------------------
// RQS spline evaluation for one element, given its 23 params in prm[].
// ---------------------------------------------------------------------------
__device__ __forceinline__ void rqs_eval(const float* prm, float xv,
                                         float& yv_out, float& lad_out)
{
    const float xin = fminf(fmaxf(xv, -3.f), 3.f);

    float mw = prm[0], mh = prm[8];
#pragma unroll
    for (int j = 1; j < 8; ++j) { mw = fmaxf(mw, prm[j]); mh = fmaxf(mh, prm[8 + j]); }
    float ew[8], eh[8];
    float sw = 0.f, sh = 0.f;
#pragma unroll
    for (int j = 0; j < 8; ++j) {
        ew[j] = expf(prm[j] - mw);      sw += ew[j];
        eh[j] = expf(prm[8 + j] - mh);  sh += eh[j];
    }
    const float rw = 1.f / sw, rh = 1.f / sh;

    const float CONST_D = logf(expf(0.999f) - 1.f);

    float cumw = 0.f, cumh = 0.f;
    float cw_lo = -3.f, ch_lo = -3.f;
    float in_cw = 0.f, in_w = 1.f, in_ch = 0.f, in_h = 1.f, sd0 = 0.f, sd1 = 0.f;
#pragma unroll
    for (int i = 0; i < 8; ++i) {
        cumw += fmaf(0.992f, ew[i] * rw, 0.001f);
        cumh += fmaf(0.992f, eh[i] * rh, 0.001f);
        const float cw_hi = (i == 7) ? 3.f : fmaf(6.f, cumw, -3.f);
        const float ch_hi = (i == 7) ? 3.f : fmaf(6.f, cumh, -3.f);
        const bool sel = (xin >= cw_lo) && ((i == 7) || (xin < cw_hi));
        in_cw = sel ? cw_lo : in_cw;
        in_w  = sel ? (cw_hi - cw_lo) : in_w;
        in_ch = sel ? ch_lo : in_ch;
        in_h  = sel ? (ch_hi - ch_lo) : in_h;
        sd0   = sel ? ((i == 0) ? CONST_D : prm[16 + i - 1]) : sd0;
        sd1   = sel ? ((i == 7) ? CONST_D : prm[16 + i]) : sd1;
        cw_lo = cw_hi; ch_lo = ch_hi;
    }

    const float d0 = 0.001f + ((sd0 > 20.f) ? sd0 : log1pf(expf(sd0)));
    const float d1 = 0.001f + ((sd1 > 20.f) ? sd1 : log1pf(expf(sd1)));

    const float delta = in_h / in_w;
    const float theta = (xin - in_cw) / in_w;
    const float omt = 1.f - theta;
    const float tom = theta * omt;
    const float th2 = theta * theta;
    const float numer = in_h * (delta * th2 + d0 * tom);
    const float denom = delta + (d0 + d1 - 2.f * delta) * tom;
    float yv = in_ch + numer / denom;
    const float dnum = delta * delta * (d1 * th2 + 2.f * delta * tom + d0 * omt * omt);
    float lad = logf(dnum) - 2.f * logf(denom);

    const bool inside = (xv >= -3.f) && (xv <= 3.f);
    yv_out = inside ? yv : xv;
    lad_out = inside ? lad : 0.f;
}

// ---------------------------------------------------------------------------
// conv3 v6: BOTH operands from LDS in the K-loop (no global latency in the
// MFMA chain). cc-outer / t-inner: act chunk (6 padded rows x 66 x 32ci =
// 25344 B, contiguous in h2p) staged once per cc; wt (9216 B per (t,cc))
// double-buffered. Per chunk: 13 ds_read_b128 + 36 MFMA. Epilogue FULLY
// UNROLLED over pt (constant acc indices — the round-3/5 spill trap),
// epi stride 148 to reduce bank conflicts.
// GEMM: M=pixels (tile 256), N=oc' 288 (2 cols x 144), K=1152 (9 t x 128 ci)
// ---------------------------------------------------------------------------
__global__ __launch_bounds__(256, 2) void conv3_rqs_k(
    const _Float16* __restrict__ h2p, const _Float16* __restrict__ w3h,
    const float* __restrict__ b3, const float* __restrict__ x,
    float* __restrict__ y, float* __restrict__ ld_out)
{
    __shared__ __align__(16) char smem[44352];
    // act [0,25344)  wt0 [25344,34560)  wt1 [34560,43776)  b3l [43776,44352)
    // epilogue overlay: epi 4 waves x 2368 floats = [0,37888)
    float* b3l = (float*)(smem + 43776);

    const int tid = threadIdx.x;
    const int wv = tid >> 6, lane = tid & 63;
    const int row16 = lane & 15, quad = lane >> 4;
    const int col = blockIdx.x;            // 0..1 -> oc' base col*144, ch col*6..+5
    const int ptile = blockIdx.y;
    const int b = ptile >> 4;
    const int pim0 = (ptile & 15) << 8;
    const int h0 = pim0 >> 6;              // base row, multiple of 4

    if (tid < 144) {
        const int c = tid / 24, j = tid % 24;
        b3l[tid] = (j < 23) ? b3[(col * 6 + c) * 23 + j] : 0.f;
    }

    f32x4 acc[4][9];
#pragma unroll
    for (int pt = 0; pt < 4; ++pt)
#pragma unroll
        for (int ot = 0; ot < 9; ++ot) acc[pt][ot] = (f32x4){0.f, 0.f, 0.f, 0.f};

    // ---- staging helpers (contiguous global->LDS via global_load_lds) ----
    auto stage_wt = [&](int t, int cc, int buf) {
        const _Float16* g = w3h + ((size_t)((t * 4 + cc) * 288 + col * 144) << 5);
        char* wb = smem + 25344 + buf * 9216;            // 576 chunks of 16B
        ASYNC16(g + (size_t)tid * 8, wb + wv * 64 * 16);
        ASYNC16(g + (size_t)(256 + tid) * 8, wb + (256 + wv * 64) * 16);
        if (wv == 0) ASYNC16(g + (size_t)(512 + lane) * 8, wb + 512 * 16);
    };
    auto stage_act = [&](int cc) {
        const _Float16* ga = h2p + H2P_IDX(b, cc, h0 * 66);   // 25344 B contiguous
#pragma unroll
        for (int k = 0; k < 6; ++k)
            ASYNC16(ga + (size_t)(k * 256 + tid) * 8, smem + (k * 256 + wv * 64) * 16);
        if (wv == 0 && lane < 48)
            ASYNC16(ga + (size_t)(1536 + lane) * 8, smem + 1536 * 16);
    };

    stage_act(0);
    stage_wt(0, 0, 0);

    for (int cc = 0; cc < 4; ++cc) {
        for (int t = 0; t < 9; ++t) {
            const int step = cc * 9 + t;
            __syncthreads();               // staged data ready; other wt buf free
            if (step + 1 < 36)
                stage_wt((t == 8) ? 0 : t + 1, (t == 8) ? cc + 1 : cc, (step + 1) & 1);
            const _Float16* act = (const _Float16*)smem;
            const _Float16* wt = (const _Float16*)(smem + 25344 + (step & 1) * 9216);
            const int dy = t / 3, dx = t % 3;
            const int lpp = (wv + dy) * 66 + dx + row16;
            half8 bf[4], af[9];
#pragma unroll
            for (int pt = 0; pt < 4; ++pt)
                bf[pt] = *(const half8*)(act + ((lpp + pt * 16) << 5) + quad * 8);
#pragma unroll
            for (int ot = 0; ot < 9; ++ot)
                af[ot] = *(const half8*)(wt + ((ot * 16 + row16) << 5) + quad * 8);
#pragma unroll
            for (int ot = 0; ot < 9; ++ot)
#pragma unroll
                for (int pt = 0; pt < 4; ++pt)
                    acc[pt][ot] = __builtin_amdgcn_mfma_f32_16x16x32_f16(af[ot], bf[pt], acc[pt][ot], 0, 0, 0);
            if (t == 8 && cc < 3) {
                __syncthreads();           // act buffer dead for all waves
                stage_act(cc + 1);
            }
        }
    }
    __syncthreads();   // K-loop LDS reads done; epi overlay safe

    // ---- epilogue: FULLY UNROLLED over pt (constant acc indices only) ----
    float* epi = (float*)smem + wv * 2368;     // 16 pix x 148-stride floats
    float lad_acc = 0.f;
#pragma unroll
    for (int pt = 0; pt < 4; ++pt) {
#pragma unroll
        for (int ot = 0; ot < 9; ++ot)
            *(f32x4*)(epi + row16 * 148 + ot * 16 + quad * 4) = acc[pt][ot];
        __syncthreads();
#pragma unroll 1
        for (int pass = 0; pass < 2; ++pass) {
            const int idx = pass * 64 + lane;
            if (idx < 96) {
                const int p16 = idx & 15, c = idx >> 4;       // c 0..5
                float prm[23];
#pragma unroll
                for (int j = 0; j < 23; ++j)
                    prm[j] = epi[p16 * 148 + c * 24 + j] + b3l[c * 24 + j];
                const int tpix = wv * 64 + pt * 16 + p16;
                const size_t xi = (((size_t)(b * 12 + col * 6 + c)) << 12) + (pim0 + tpix);
                const float xv = x[xi];
                float yv, lad;
                rqs_eval(prm, xv, yv, lad);
                y[xi] = yv;
                lad_acc += lad;
            }
        }
        __syncthreads();   // epi region reuse across pt
    }

#pragma unroll
    for (int off = 32; off > 0; off >>= 1) lad_acc += __shfl_down(lad_acc, off);
    if (lane == 0) atomicAdd(&ld_out[b], lad_acc);
}

// ---------------------------------------------------------------------------
extern "C" void kernel_launch(void* const* d_in, const int* in_sizes, int n_in,
                              void* d_out, int out_size, void* d_ws, size_t ws_size,
                              hipStream_t stream)
{
    const float* x      = (const float*)d_in[0];
    const float* logdet = (const float*)d_in[1];
    const float* cond   = (const float*)d_in[2];
    const float* w1     = (const float*)d_in[3];
    const float* b1     = (const float*)d_in[4];
    const float* w2     = (const float*)d_in[5];
    const float* b2     = (const float*)d_in[6];
    const float* w3     = (const float*)d_in[7];
    const float* b3     = (const float*)d_in[8];

    char* ws = (char*)d_ws;
    _Float16* h1p = (_Float16*)ws;                       // 33,554,432 B  [b][pix][128oc]
    _Float16* h2p = (_Float16*)(ws + 33554432);          // 35,684,352 B
    _Float16* xh  = (_Float16*)(ws + 33554432);          // 8,921,088 B — ALIASES h2p
                                                         // (consumed by conv1 before
                                                         //  zring/conv2 write h2p)
    _Float16* w1h = (_Float16*)(ws + 69238784);          // 73,728 B
    _Float16* w2h = (_Float16*)(ws + 69312512);          // 32,768 B
    _Float16* w3h = (_Float16*)(ws + 69345280);          // 663,552 B (end ~70 MB)

    float* y      = (float*)d_out;                       // NY floats
    float* ld_out = y + NY;                              // 32 floats

    prep_k<<<1296, 256, 0, stream>>>(w1, w2, w3, w1h, w2h, w3h, logdet, ld_out);
    xh_k<<<545, 256, 0, stream>>>(x, cond, xh);
    conv1_k<<<512, 256, 0, stream>>>(xh, w1h, b1, h1p);
    zring_k<<<520, 256, 0, stream>>>(h2p);
    conv2_k<<<512, 256, 0, stream>>>(h1p, w2h, b2, h2p);
    conv3_rqs_k<<<dim3(2, 512), 256, 0, stream>>>(h2p, w3h, b3, x, y, ld_out);
}